// Round 1
// baseline (367.089 us; speedup 1.0000x reference)
//
#include <hip/hip_runtime.h>

// DE3: entropy-based scalar from a 256-bin histogram of floor(img) over the
// whole (16,2048,2048) fp32 tensor, p normalized by H*W (NOT B*H*W).
// out[0] = B * (8 + sum_i p_i*log2(p_i)),  p_i = count_i / (H*W).
//
// Memory-bound streaming reduction: 268 MB read -> ~43 us floor @6.3 TB/s.

#define NBINS 256
#define HIST_BLOCKS 2048
#define HIST_THREADS 256

__global__ void zero_hist(unsigned int* __restrict__ hist) {
    // 1 block x 256 threads: zero the global histogram in d_ws (re-poisoned
    // to 0xAA before every timed launch).
    hist[threadIdx.x] = 0u;
}

__global__ __launch_bounds__(HIST_THREADS) void hist_kernel(
        const float* __restrict__ img,
        unsigned int* __restrict__ ghist,
        int n_vec4, long long n_total) {
    // One private LDS histogram per wave (4 waves/block) to reduce
    // same-address LDS-atomic serialization across waves. 4 KiB LDS/block.
    __shared__ unsigned int lhist[4][NBINS];
    const int wave = threadIdx.x >> 6;

    for (int i = threadIdx.x; i < 4 * NBINS; i += HIST_THREADS)
        ((unsigned int*)lhist)[i] = 0u;
    __syncthreads();

    const float4* __restrict__ img4 = (const float4*)img;
    const int tid = blockIdx.x * HIST_THREADS + threadIdx.x;
    const int stride = gridDim.x * HIST_THREADS;

    // Main vectorized loop: 16 B/lane coalesced loads (G13).
    for (int i = tid; i < n_vec4; i += stride) {
        float4 v = img4[i];
        // values are in [0,256); guard anyway to match reference's
        // out-of-range exclusion. truncation == floor for v >= 0.
        if (v.x >= 0.0f && v.x < 256.0f) atomicAdd(&lhist[wave][(int)v.x], 1u);
        if (v.y >= 0.0f && v.y < 256.0f) atomicAdd(&lhist[wave][(int)v.y], 1u);
        if (v.z >= 0.0f && v.z < 256.0f) atomicAdd(&lhist[wave][(int)v.z], 1u);
        if (v.w >= 0.0f && v.w < 256.0f) atomicAdd(&lhist[wave][(int)v.w], 1u);
    }
    // Scalar tail (n_total % 4 != 0); no-op for this problem size.
    for (long long j = 4LL * n_vec4 + tid; j < n_total; j += stride) {
        float v = img[j];
        if (v >= 0.0f && v < 256.0f) atomicAdd(&lhist[wave][(int)v], 1u);
    }

    __syncthreads();
    // Merge the 4 wave-copies and push one global atomic per bin per block.
    // 2048 blocks * 256 bins = 524K global atomics, staggered by block drain.
    unsigned int s = lhist[0][threadIdx.x] + lhist[1][threadIdx.x] +
                     lhist[2][threadIdx.x] + lhist[3][threadIdx.x];
    if (s) atomicAdd(&ghist[threadIdx.x], s);
}

__global__ void entropy_kernel(const unsigned int* __restrict__ ghist,
                               float* __restrict__ out,
                               float B, float inv_temp) {
    const int t = threadIdx.x;  // 256 threads, one bin each
    unsigned int c = ghist[t];
    float term = 0.0f;
    if (c > 0u) {
        float p = (float)c * inv_temp;
        term = p * __log2f(p);  // fast log2; error way under the 17.92 threshold
    }
    // wave64 shuffle reduce, then cross-wave via LDS
    #pragma unroll
    for (int off = 32; off > 0; off >>= 1)
        term += __shfl_down(term, off, 64);
    __shared__ float wsum[4];
    if ((t & 63) == 0) wsum[t >> 6] = term;
    __syncthreads();
    if (t == 0) {
        float s = wsum[0] + wsum[1] + wsum[2] + wsum[3];
        out[0] = B * (8.0f + s);  // res = -s  ->  B*(8-res) = B*(8+s)
    }
}

extern "C" void kernel_launch(void* const* d_in, const int* in_sizes, int n_in,
                              void* d_out, int out_size, void* d_ws, size_t ws_size,
                              hipStream_t stream) {
    const float* img = (const float*)d_in[0];
    float* out = (float*)d_out;
    unsigned int* ghist = (unsigned int*)d_ws;  // 1 KiB of scratch

    const long long n = (long long)in_sizes[0];       // B*H*W = 67,108,864
    const long long HW = 2048LL * 2048LL;             // temp = H*W (fixed problem shape)
    const float B = (float)(n / HW);                  // 16
    const float inv_temp = 1.0f / (float)HW;
    const int n_vec4 = (int)(n / 4);

    zero_hist<<<dim3(1), dim3(NBINS), 0, stream>>>(ghist);
    hist_kernel<<<dim3(HIST_BLOCKS), dim3(HIST_THREADS), 0, stream>>>(
        img, ghist, n_vec4, n);
    entropy_kernel<<<dim3(1), dim3(NBINS), 0, stream>>>(ghist, out, B, inv_temp);
}